// Round 1
// baseline (1489.245 us; speedup 1.0000x reference)
//
#include <hip/hip_runtime.h>

// Problem constants (fixed by reference)
#define NV 10000   // vertices
#define NR 5       // R
#define NA 8       // A
#define NC 64      // C (= T)
#define NK 2560    // K = R*A*C
#define NT 512     // N = A*T
#define BK 16      // K-chunk
#define MT 16      // vertices per block

// 1/sqrt(1 + 1e-3), the BN "inv" factor
#define BN_INV 0.99950037468777316f

// Build W[k=(r,a,c)][n=(o,t)] = T[t, r, (o+a)%8, c] for both stages.
__global__ void build_w_kernel(const float* __restrict__ t1,
                               const float* __restrict__ t2,
                               float* __restrict__ W1,
                               float* __restrict__ W2) {
    const int k = blockIdx.x;       // 0..2559
    const int n = threadIdx.x;      // 0..511
    const int r = k >> 9;           // k / 512
    const int a = (k >> 6) & 7;
    const int c = k & 63;
    const int o = n >> 6;
    const int t = n & 63;
    const int oa = (o + a) & 7;
    const float* T = blockIdx.y ? t2 : t1;
    float*       W = blockIdx.y ? W2 : W1;
    W[k * NT + n] = T[((t * NR + r) * NA + oa) * NC + c];
}

// One conv_dirac stage fused with angular-max-pool + BN (+residual) + ReLU.
// Block: 256 threads = 4 waves. Wave tm owns rows vbase+tm*4 .. +3.
// Lane tn owns output column t = tn for all 8 o's: acc[i][j] = S[v, o=j, t=tn].
template<bool RES>
__global__ __launch_bounds__(256, 2)
void stage_kernel(const float* __restrict__ src,      // gather source, rows of 64
                  const int*   __restrict__ bc_idx,   // (V,R,A,3)
                  const float* __restrict__ bc_w,     // (V,R,A,3)
                  const float* __restrict__ W,        // (K, NT)
                  const float* __restrict__ bias,     // (64)
                  const float* __restrict__ gamma,    // (64)
                  const float* __restrict__ beta,     // (64)
                  const float* __restrict__ resid,    // (V,64) or null
                  float*       __restrict__ dst) {    // (V,64)
    __shared__ float sW[BK * NT];   // 32 KB: W chunk, [kk][n]
    __shared__ float sI[MT * BK];   // 1 KB: interp chunk, [m][kk]

    const int x  = threadIdx.x;
    const int tm = x >> 6;          // wave id 0..3
    const int tn = x & 63;          // lane id = output t
    const int vbase = blockIdx.x * MT;

    float acc[4][8];
    const float bt = bias[tn];
    #pragma unroll
    for (int i = 0; i < 4; ++i)
        #pragma unroll
        for (int j = 0; j < 8; ++j) acc[i][j] = bt;

    // interp-phase assignment: thread -> (m, kk)
    const int im = x >> 4;          // 0..15
    const int ik = x & 15;          // 0..15
    const int iv = vbase + im;

    for (int chunk = 0; chunk < NK / BK; ++chunk) {
        const int k0 = chunk * BK;
        __syncthreads();            // LDS free from previous chunk's reads

        // Stage W chunk: contiguous 16*512 floats -> LDS, float4-coalesced.
        {
            const float4* swp = (const float4*)(W + (size_t)k0 * NT);
            float4*       dwp = (float4*)sW;
            #pragma unroll
            for (int j = 0; j < 8; ++j) dwp[x + 256 * j] = swp[x + 256 * j];
        }
        // Interp chunk: one (m,kk) element per thread. A BK=16 chunk stays
        // within a single (r,a), so one idx/w triple per (v, chunk).
        {
            const int ra = k0 >> 6;            // (r*8+a)
            const int c  = (k0 & 63) + ik;     // column within gathered rows
            const int*   ip = bc_idx + (size_t)iv * (NR * NA * 3) + ra * 3;
            const float* wp = bc_w  + (size_t)iv * (NR * NA * 3) + ra * 3;
            const float g = wp[0] * src[ip[0] * NC + c]
                          + wp[1] * src[ip[1] * NC + c]
                          + wp[2] * src[ip[2] * NC + c];
            sI[im * BK + ik] = g;
        }
        __syncthreads();

        // FMA: per 4-k group: 4 x b128 broadcast (sI) + 32 x b32 (sW, 2-way
        // free aliasing) -> 128 FMAs.
        #pragma unroll
        for (int kq = 0; kq < BK; kq += 4) {
            float4 ar[4];
            #pragma unroll
            for (int i = 0; i < 4; ++i)
                ar[i] = *(const float4*)(sI + (tm * 4 + i) * BK + kq);
            #pragma unroll
            for (int q = 0; q < 4; ++q) {
                const float* wrow = sW + (kq + q) * NT + tn;
                #pragma unroll
                for (int j = 0; j < 8; ++j) {
                    const float w = wrow[64 * j];
                    #pragma unroll
                    for (int i = 0; i < 4; ++i)
                        acc[i][j] = fmaf(((const float*)&ar[i])[q], w, acc[i][j]);
                }
            }
        }
    }

    // Epilogue: angular max-pool + BN (+residual) + ReLU, all in registers.
    // norm^2[v, o=j] = sum over t (= lanes) of acc[i][j]^2.
    #pragma unroll
    for (int i = 0; i < 4; ++i) {
        float n2[8];
        #pragma unroll
        for (int j = 0; j < 8; ++j) {
            float v2 = acc[i][j] * acc[i][j];
            #pragma unroll
            for (int off = 1; off < 64; off <<= 1)
                v2 += __shfl_xor(v2, off, 64);
            n2[j] = v2;             // replicated on all lanes
        }
        // argmax over o (first-max tie-break, matching jnp.argmax)
        int bj = 0; float bv = n2[0];
        #pragma unroll
        for (int j = 1; j < 8; ++j) {
            if (n2[j] > bv) { bv = n2[j]; bj = j; }
        }
        float val = acc[i][0];
        #pragma unroll
        for (int j = 1; j < 8; ++j) val = (bj == j) ? acc[i][j] : val;

        const int v = vbase + tm * 4 + i;
        float r = gamma[tn] * (val * BN_INV) + beta[tn];
        if (RES) r += resid[(size_t)v * NC + tn];
        r = fmaxf(r, 0.0f);
        dst[(size_t)v * NC + tn] = r;
    }
}

extern "C" void kernel_launch(void* const* d_in, const int* in_sizes, int n_in,
                              void* d_out, int out_size, void* d_ws, size_t ws_size,
                              hipStream_t stream) {
    const float* signal = (const float*)d_in[0];
    const float* bc_w   = (const float*)d_in[1];
    const float* t1     = (const float*)d_in[2];
    const float* bias1  = (const float*)d_in[3];
    const float* gamma1 = (const float*)d_in[4];
    const float* beta1  = (const float*)d_in[5];
    const float* t2     = (const float*)d_in[6];
    const float* bias2  = (const float*)d_in[7];
    const float* gamma2 = (const float*)d_in[8];
    const float* beta2  = (const float*)d_in[9];
    const int*   bc_idx = (const int*)d_in[10];

    float* W1 = (float*)d_ws;                     // 2560*512 f32 = 5.24 MB
    float* W2 = W1 + (size_t)NK * NT;             // 5.24 MB
    float* s  = W2 + (size_t)NK * NT;             // V*64 f32 = 2.56 MB
    float* out = (float*)d_out;

    build_w_kernel<<<dim3(NK, 2), NT, 0, stream>>>(t1, t2, W1, W2);

    stage_kernel<false><<<NV / MT, 256, 0, stream>>>(
        signal, bc_idx, bc_w, W1, bias1, gamma1, beta1, nullptr, s);

    stage_kernel<true><<<NV / MT, 256, 0, stream>>>(
        s, bc_idx, bc_w, W2, bias2, gamma2, beta2, signal, out);
}

// Round 2
// 1368.302 us; speedup vs baseline: 1.0884x; 1.0884x over previous
//
#include <hip/hip_runtime.h>

// Problem constants (fixed by reference)
#define NV 10000   // vertices
#define NR 5       // R
#define NA 8       // A
#define NC 64      // C (= T)
#define NK 2560    // K = R*A*C
#define NT 512     // N = A*T
#define BK 16      // K-chunk
#define MT 16      // vertices per block

// 1/sqrt(1 + 1e-3), the BN "inv" factor
#define BN_INV 0.99950037468777316f

#define AS1 __attribute__((address_space(1)))
#define AS3 __attribute__((address_space(3)))

// Build W[k=(r,a,c)][n=(o,t)] = T[t, r, (o+a)%8, c] for both stages.
__global__ void build_w_kernel(const float* __restrict__ t1,
                               const float* __restrict__ t2,
                               float* __restrict__ W1,
                               float* __restrict__ W2) {
    const int k = blockIdx.x;       // 0..2559
    const int n = threadIdx.x;      // 0..511
    const int r = k >> 9;           // k / 512
    const int a = (k >> 6) & 7;
    const int c = k & 63;
    const int o = n >> 6;
    const int t = n & 63;
    const int oa = (o + a) & 7;
    const float* T = blockIdx.y ? t2 : t1;
    float*       W = blockIdx.y ? W2 : W1;
    W[k * NT + n] = T[((t * NR + r) * NA + oa) * NC + c];
}

// One conv_dirac stage fused with angular-max-pool + BN (+residual) + ReLU.
// Block: 256 threads = 4 waves, MT=16 rows, full N=512.
// Wave wj owns n in [128*wj, 128*wj+128): o in {2wj, 2wj+1}, t = lane tn.
// acc0[m] = S[v_m, o=2wj,   t=tn], acc1[m] = S[v_m, o=2wj+1, t=tn].
template<bool RES>
__global__ __launch_bounds__(256, 2)
void stage_kernel(const float* __restrict__ src,      // gather source, rows of 64
                  const int*   __restrict__ bc_idx,   // (V,R,A,3)
                  const float* __restrict__ bc_w,     // (V,R,A,3)
                  const float* __restrict__ W,        // (K, NT)
                  const float* __restrict__ bias,     // (64)
                  const float* __restrict__ gamma,    // (64)
                  const float* __restrict__ beta,     // (64)
                  const float* __restrict__ resid,    // (V,64) or null
                  float*       __restrict__ dst) {    // (V,64)
    __shared__ float sW[BK * NT];   // 32 KB: W chunk, [kk][n]
    __shared__ float sI[MT * BK];   // 1 KB: interp chunk, [m][kk]
    __shared__ float sN[MT * NA];   // 0.5 KB: norms^2 for pooling

    const int x  = threadIdx.x;
    const int wj = x >> 6;          // wave id 0..3 -> o-pair
    const int tn = x & 63;          // lane id = output t
    const int vbase = blockIdx.x * MT;

    float acc0[MT], acc1[MT];
    const float bt = bias[tn];      // bias depends only on t for both cols
    #pragma unroll
    for (int m = 0; m < MT; ++m) { acc0[m] = bt; acc1[m] = bt; }

    // interp-phase assignment: thread -> (m, kk)
    const int im = x >> 4;          // 0..15
    const int ik = x & 15;          // 0..15
    const int iv = vbase + im;

    const float* sWw = sW + wj * 128 + tn;   // this wave's w column base

    for (int chunk = 0; chunk < NK / BK; ++chunk) {
        const int k0 = chunk * BK;
        __syncthreads();            // LDS free from previous chunk's reads

        // Stage W chunk: contiguous 16*512 floats -> LDS, async 16B/lane.
        {
            const float4* gsrc = (const float4*)(W + (size_t)k0 * NT) + x;
            float4*       ldst = ((float4*)sW) + x;
            #pragma unroll
            for (int j = 0; j < 8; ++j)
                __builtin_amdgcn_global_load_lds((AS1 const void*)(gsrc + 256 * j),
                                                 (AS3 void*)(ldst + 256 * j),
                                                 16, 0, 0);
        }
        // Interp chunk: one (m,kk) element per thread. A BK=16 chunk stays
        // within a single (r,a), so one idx/w triple per (v, chunk).
        {
            const int ra = k0 >> 6;            // (r*8+a)
            const int c  = (k0 & 63) + ik;     // column within gathered rows
            const int*   ip = bc_idx + (size_t)iv * (NR * NA * 3) + ra * 3;
            const float* wp = bc_w  + (size_t)iv * (NR * NA * 3) + ra * 3;
            const float g = wp[0] * src[ip[0] * NC + c]
                          + wp[1] * src[ip[1] * NC + c]
                          + wp[2] * src[ip[2] * NC + c];
            sI[im * BK + ik] = g;
        }
        __syncthreads();

        // Inner: per 4-k group: 8 w-reads (b32, 2-way free) + 16 uniform
        // b128 broadcasts (a) -> 128 FMAs/lane.
        #pragma unroll
        for (int kq = 0; kq < BK; kq += 4) {
            float w0[4], w1[4];
            #pragma unroll
            for (int q = 0; q < 4; ++q) {
                w0[q] = sWw[(kq + q) * NT];
                w1[q] = sWw[(kq + q) * NT + 64];
            }
            #pragma unroll
            for (int mg = 0; mg < 4; ++mg) {
                float4 av[4];
                #pragma unroll
                for (int m = 0; m < 4; ++m)
                    av[m] = *(const float4*)(sI + (mg * 4 + m) * BK + kq);
                #pragma unroll
                for (int m = 0; m < 4; ++m) {
                    const float* ap = (const float*)&av[m];
                    #pragma unroll
                    for (int q = 0; q < 4; ++q) {
                        acc0[mg * 4 + m] = fmaf(ap[q], w0[q], acc0[mg * 4 + m]);
                        acc1[mg * 4 + m] = fmaf(ap[q], w1[q], acc1[mg * 4 + m]);
                    }
                }
            }
        }
    }

    // Epilogue: norms^2 per (row, o) via 64-lane butterfly; exchange across
    // waves through LDS; argmax over o; winning wave applies BN(+res)+ReLU.
    #pragma unroll
    for (int m = 0; m < MT; ++m) {
        float va = acc0[m] * acc0[m];
        float vb = acc1[m] * acc1[m];
        #pragma unroll
        for (int off = 1; off < 64; off <<= 1) {
            va += __shfl_xor(va, off, 64);
            vb += __shfl_xor(vb, off, 64);
        }
        if (tn == 0) {
            sN[m * NA + 2 * wj]     = va;
            sN[m * NA + 2 * wj + 1] = vb;
        }
    }
    __syncthreads();

    #pragma unroll
    for (int m = 0; m < MT; ++m) {
        float bv = sN[m * NA];
        int   bj = 0;
        #pragma unroll
        for (int j = 1; j < 8; ++j) {
            const float t = sN[m * NA + j];
            if (t > bv) { bv = t; bj = j; }   // first-max tie-break (jnp.argmax)
        }
        if ((bj >> 1) == wj) {
            const float val = (bj & 1) ? acc1[m] : acc0[m];
            const int v = vbase + m;
            float r = gamma[tn] * (val * BN_INV) + beta[tn];
            if (RES) r += resid[(size_t)v * NC + tn];
            dst[(size_t)v * NC + tn] = fmaxf(r, 0.0f);
        }
    }
}

extern "C" void kernel_launch(void* const* d_in, const int* in_sizes, int n_in,
                              void* d_out, int out_size, void* d_ws, size_t ws_size,
                              hipStream_t stream) {
    const float* signal = (const float*)d_in[0];
    const float* bc_w   = (const float*)d_in[1];
    const float* t1     = (const float*)d_in[2];
    const float* bias1  = (const float*)d_in[3];
    const float* gamma1 = (const float*)d_in[4];
    const float* beta1  = (const float*)d_in[5];
    const float* t2     = (const float*)d_in[6];
    const float* bias2  = (const float*)d_in[7];
    const float* gamma2 = (const float*)d_in[8];
    const float* beta2  = (const float*)d_in[9];
    const int*   bc_idx = (const int*)d_in[10];

    float* W1 = (float*)d_ws;                     // 2560*512 f32 = 5.24 MB
    float* W2 = W1 + (size_t)NK * NT;             // 5.24 MB
    float* s  = W2 + (size_t)NK * NT;             // V*64 f32 = 2.56 MB
    float* out = (float*)d_out;

    build_w_kernel<<<dim3(NK, 2), NT, 0, stream>>>(t1, t2, W1, W2);

    stage_kernel<false><<<NV / MT, 256, 0, stream>>>(
        signal, bc_idx, bc_w, W1, bias1, gamma1, beta1, nullptr, s);

    stage_kernel<true><<<NV / MT, 256, 0, stream>>>(
        s, bc_idx, bc_w, W2, bias2, gamma2, beta2, signal, out);
}

// Round 3
// 697.585 us; speedup vs baseline: 2.1349x; 1.9615x over previous
//
#include <hip/hip_runtime.h>

// Problem constants (fixed by reference)
#define NVV 10000    // vertices
#define NKSTEPS 80   // 2560 / 32
#define BN_INV 0.99950037468777316f

#define AS1 __attribute__((address_space(1)))
#define AS3 __attribute__((address_space(3)))

typedef float f32x4 __attribute__((ext_vector_type(4)));
typedef short short8 __attribute__((ext_vector_type(8)));

// ---------------------------------------------------------------------------
// Split a f32 into bf16 (RNE) + f32 remainder.
__device__ __forceinline__ unsigned short bsplit(float v, float& rem) {
    unsigned u = __float_as_uint(v);
    unsigned r = (u + 0x7fffu + ((u >> 16) & 1u)) & 0xffff0000u;
    rem = v - __uint_as_float(r);
    return (unsigned short)(r >> 16);
}

// ---------------------------------------------------------------------------
// W global layout (per stage): [kstep 80][strip 4] chunks of 30720 B.
// Chunk: [ntile 8][split 3][n 16][kpad 40] ushort  (k-rows padded 32->40).
// Element (k,n): W[k][n] = T[t, r, (o+a)&7, c], k=(r,a,c), n=(o,t).
__global__ void build_w_kernel(const float* __restrict__ t1,
                               const float* __restrict__ t2,
                               unsigned short* __restrict__ W1g,
                               unsigned short* __restrict__ W2g) {
    const int k = blockIdx.x;       // 0..2559
    const int n = threadIdx.x;      // 0..511
    const float*    T  = blockIdx.y ? t2 : t1;
    unsigned short* Wg = blockIdx.y ? W2g : W1g;
    const int r = k >> 9, a = (k >> 6) & 7, c = k & 63;
    const int o = n >> 6, t = n & 63;
    const float w = T[((t * 5 + r) * 8 + ((o + a) & 7)) * 64 + c];
    float r1, r2, r3;
    const unsigned short h1 = bsplit(w, r1);
    const unsigned short h2 = bsplit(r1, r2);
    const unsigned short h3 = bsplit(r2, r3);
    const int kstep = k >> 5, kk = k & 31;
    const int strip = n >> 7, nl = n & 127, ntile = nl >> 4, nn = nl & 15;
    const size_t base = (size_t)(kstep * 4 + strip) * 15360;
    const int i0 = ((ntile * 3 + 0) * 16 + nn) * 40 + kk;
    Wg[base + i0]        = h1;   // split plane stride = 16*40 = 640 ushorts
    Wg[base + i0 + 640]  = h2;
    Wg[base + i0 + 1280] = h3;
}

// ---------------------------------------------------------------------------
// Split-3 bf16 MFMA GEMM: block = 80 rows x 128 cols (one N-strip), K=2560.
// grid 500 = 125 Mgroups x 4 strips (strip-major for L2 reuse of W).
// 4 waves: wave wj owns cols [32wj,32wj+32) = n-tiles {2wj, 2wj+1}.
// Writes S (V x 512, bias included) and normsq (V x 8) for the pool kernel.
__global__ __launch_bounds__(256, 2)
void gemm_kernel(const float* __restrict__ src,      // gather source (rows of 64)
                 const int*   __restrict__ bc_idx,   // (V,R,A,3)
                 const float* __restrict__ bc_w,     // (V,R,A,3)
                 const unsigned short* __restrict__ Wg,
                 const float* __restrict__ bias,     // (64)
                 float*       __restrict__ S,        // (V,512)
                 float*       __restrict__ normsq) { // (V,8)
    __shared__ unsigned short sW[15360];  // 30720 B: W chunk in frag layout
    __shared__ unsigned short sA[9600];   // 19200 B: [mtile 5][split 3][m 16][kpad 40]
    __shared__ float sN[2][2][80];        // norms: [o_idx][wave-half][m]

    const int x      = threadIdx.x;
    const int strip  = blockIdx.x / 125;      // 0..3
    const int mg     = blockIdx.x % 125;      // 0..124
    const int Mbase  = mg * 80;
    const int wj     = x >> 6;
    const int lane   = x & 63;
    const int lane16 = lane & 15;
    const int q      = lane >> 4;

    f32x4 d[5][2] = {};                       // 40 f32 accumulators

    // interp mapping: thread -> (kquad = x&7, row base = x>>3), 5 rows apart 32
    const int kq  = x & 7;
    const int mrb = x >> 3;

    for (int ks = 0; ks < NKSTEPS; ++ks) {
        __syncthreads();   // sW/sA free from previous step's frag reads

        // ---- stage W chunk (30720 B = 1920 x 16B units) async to LDS ----
        {
            const char* gW = (const char*)Wg + (size_t)(ks * 4 + strip) * 30720;
            char*       lW = (char*)sW;
            #pragma unroll
            for (int j = 0; j < 7; ++j)
                __builtin_amdgcn_global_load_lds(
                    (AS1 const void*)(gW + (x + 256 * j) * 16),
                    (AS3 void*)(lW + (x + 256 * j) * 16), 16, 0, 0);
            if (x < 128)
                __builtin_amdgcn_global_load_lds(
                    (AS1 const void*)(gW + (x + 1792) * 16),
                    (AS3 void*)(lW + (x + 1792) * 16), 16, 0, 0);
        }

        // ---- interp chunk: gather+blend 4 k's per item, split-3, -> LDS ----
        {
            const int ra = ks >> 1;                  // (r*8+a) for this chunk
            const int c0 = (ks & 1) * 32 + kq * 4;   // column within src rows
            #pragma unroll
            for (int i = 0; i < 5; ++i) {
                const int m = mrb + 32 * i;
                const int v = Mbase + m;
                const int*   ip = bc_idx + v * 120 + ra * 3;
                const float* wp = bc_w  + v * 120 + ra * 3;
                const int   i0 = ip[0], i1 = ip[1], i2 = ip[2];
                const float w0 = wp[0], w1 = wp[1], w2 = wp[2];
                const float4 g0 = *(const float4*)(src + (size_t)i0 * 64 + c0);
                const float4 g1 = *(const float4*)(src + (size_t)i1 * 64 + c0);
                const float4 g2 = *(const float4*)(src + (size_t)i2 * 64 + c0);
                unsigned short h1[4], h2[4], h3[4];
                const float gv0[4] = {g0.x, g0.y, g0.z, g0.w};
                const float gv1[4] = {g1.x, g1.y, g1.z, g1.w};
                const float gv2[4] = {g2.x, g2.y, g2.z, g2.w};
                #pragma unroll
                for (int e = 0; e < 4; ++e) {
                    const float vv = w0 * gv0[e] + w1 * gv1[e] + w2 * gv2[e];
                    float rm1, rm2, rm3;
                    h1[e] = bsplit(vv, rm1);
                    h2[e] = bsplit(rm1, rm2);
                    h3[e] = bsplit(rm2, rm3);
                }
                const int mt = m >> 4, mm = m & 15;
                const int b0 = ((mt * 3 + 0) * 16 + mm) * 40 + kq * 4; // ushort units
                *(uint2*)(sA + b0)        = make_uint2((unsigned)h1[0] | ((unsigned)h1[1] << 16),
                                                       (unsigned)h1[2] | ((unsigned)h1[3] << 16));
                *(uint2*)(sA + b0 + 640)  = make_uint2((unsigned)h2[0] | ((unsigned)h2[1] << 16),
                                                       (unsigned)h2[2] | ((unsigned)h2[3] << 16));
                *(uint2*)(sA + b0 + 1280) = make_uint2((unsigned)h3[0] | ((unsigned)h3[1] << 16),
                                                       (unsigned)h3[2] | ((unsigned)h3[3] << 16));
            }
        }
        __syncthreads();   // W DMA drained + interp visible

        // ---- MFMA: 6 split-products per (mtile, ntile) ----
        short8 b[2][3];
        #pragma unroll
        for (int nt = 0; nt < 2; ++nt)
            #pragma unroll
            for (int sp = 0; sp < 3; ++sp)
                b[nt][sp] = *(const short8*)(sW + (((2 * wj + nt) * 3 + sp) * 16 + lane16) * 40 + q * 8);
        #pragma unroll
        for (int mt = 0; mt < 5; ++mt) {
            const short8 a1 = *(const short8*)(sA + ((mt * 3 + 0) * 16 + lane16) * 40 + q * 8);
            const short8 a2 = *(const short8*)(sA + ((mt * 3 + 1) * 16 + lane16) * 40 + q * 8);
            const short8 a3 = *(const short8*)(sA + ((mt * 3 + 2) * 16 + lane16) * 40 + q * 8);
            #pragma unroll
            for (int nt = 0; nt < 2; ++nt) {
                d[mt][nt] = __builtin_amdgcn_mfma_f32_16x16x32_bf16(a1, b[nt][0], d[mt][nt], 0, 0, 0);
                d[mt][nt] = __builtin_amdgcn_mfma_f32_16x16x32_bf16(a1, b[nt][1], d[mt][nt], 0, 0, 0);
                d[mt][nt] = __builtin_amdgcn_mfma_f32_16x16x32_bf16(a2, b[nt][0], d[mt][nt], 0, 0, 0);
                d[mt][nt] = __builtin_amdgcn_mfma_f32_16x16x32_bf16(a2, b[nt][1], d[mt][nt], 0, 0, 0);
                d[mt][nt] = __builtin_amdgcn_mfma_f32_16x16x32_bf16(a3, b[nt][0], d[mt][nt], 0, 0, 0);
                d[mt][nt] = __builtin_amdgcn_mfma_f32_16x16x32_bf16(a1, b[nt][2], d[mt][nt], 0, 0, 0);
            }
        }
    }

    // ---- epilogue: +bias, store S, norms^2, cross-wave reduce, normsq ----
    float bs[2];
    #pragma unroll
    for (int nt = 0; nt < 2; ++nt)
        bs[nt] = bias[(32 * wj + 16 * nt + lane16) & 63];

    float p[5][4];
    #pragma unroll
    for (int mt = 0; mt < 5; ++mt)
        #pragma unroll
        for (int r = 0; r < 4; ++r) p[mt][r] = 0.0f;

    #pragma unroll
    for (int mt = 0; mt < 5; ++mt) {
        #pragma unroll
        for (int nt = 0; nt < 2; ++nt) {
            #pragma unroll
            for (int r = 0; r < 4; ++r) {
                const float val = d[mt][nt][r] + bs[nt];
                const int mglob = Mbase + mt * 16 + q * 4 + r;
                const int nglob = strip * 128 + wj * 32 + nt * 16 + lane16;
                S[(size_t)mglob * 512 + nglob] = val;
                p[mt][r] += val * val;
            }
        }
    }
    // reduce over the 16 lanes sharing q (cols) -> 32-col partials
    #pragma unroll
    for (int mt = 0; mt < 5; ++mt)
        #pragma unroll
        for (int r = 0; r < 4; ++r) {
            float v = p[mt][r];
            v += __shfl_xor(v, 1, 64);
            v += __shfl_xor(v, 2, 64);
            v += __shfl_xor(v, 4, 64);
            v += __shfl_xor(v, 8, 64);
            p[mt][r] = v;
        }
    if (lane16 == 0) {
        #pragma unroll
        for (int mt = 0; mt < 5; ++mt)
            #pragma unroll
            for (int r = 0; r < 4; ++r)
                sN[wj >> 1][wj & 1][mt * 16 + q * 4 + r] = p[mt][r];
    }
    __syncthreads();
    if (x < 80) {
        const int v = Mbase + x;
        normsq[(size_t)v * 8 + strip * 2]     = sN[0][0][x] + sN[0][1][x];
        normsq[(size_t)v * 8 + strip * 2 + 1] = sN[1][0][x] + sN[1][1][x];
    }
}

// ---------------------------------------------------------------------------
// Angular max-pool + BN (+residual) + ReLU. One thread per (v, t).
template<bool RES>
__global__ void pool_kernel(const float* __restrict__ S,
                            const float* __restrict__ normsq,
                            const float* __restrict__ gamma,
                            const float* __restrict__ beta,
                            const float* __restrict__ resid,
                            float*       __restrict__ dst) {
    const int gid = blockIdx.x * 256 + threadIdx.x;   // 640000 = 2500*256
    const int v = gid >> 6, t = gid & 63;
    const float* nv = normsq + (size_t)v * 8;
    float bv = nv[0];
    int   bj = 0;
    #pragma unroll
    for (int j = 1; j < 8; ++j) {
        const float tv = nv[j];
        if (tv > bv) { bv = tv; bj = j; }   // first-max tie-break (jnp.argmax)
    }
    const float val = S[(size_t)v * 512 + bj * 64 + t];
    float r = gamma[t] * (val * BN_INV) + beta[t];
    if (RES) r += resid[(size_t)v * 64 + t];
    dst[(size_t)v * 64 + t] = fmaxf(r, 0.0f);
}

// ---------------------------------------------------------------------------
extern "C" void kernel_launch(void* const* d_in, const int* in_sizes, int n_in,
                              void* d_out, int out_size, void* d_ws, size_t ws_size,
                              hipStream_t stream) {
    const float* signal = (const float*)d_in[0];
    const float* bc_w   = (const float*)d_in[1];
    const float* t1     = (const float*)d_in[2];
    const float* bias1  = (const float*)d_in[3];
    const float* gamma1 = (const float*)d_in[4];
    const float* beta1  = (const float*)d_in[5];
    const float* t2     = (const float*)d_in[6];
    const float* bias2  = (const float*)d_in[7];
    const float* gamma2 = (const float*)d_in[8];
    const float* beta2  = (const float*)d_in[9];
    const int*   bc_idx = (const int*)d_in[10];

    // workspace: W1g (9.83 MB) | W2g (9.83 MB) | S (20.48 MB) | normsq (320 KB) | s1 (2.56 MB)
    unsigned short* W1g = (unsigned short*)d_ws;
    unsigned short* W2g = W1g + (size_t)80 * 4 * 15360;
    float* S      = (float*)(W2g + (size_t)80 * 4 * 15360);
    float* normsq = S + (size_t)NVV * 512;
    float* s1     = normsq + (size_t)NVV * 8;
    float* out    = (float*)d_out;

    build_w_kernel<<<dim3(2560, 2), 512, 0, stream>>>(t1, t2, W1g, W2g);

    gemm_kernel<<<500, 256, 0, stream>>>(signal, bc_idx, bc_w, W1g, bias1, S, normsq);
    pool_kernel<false><<<2500, 256, 0, stream>>>(S, normsq, gamma1, beta1, nullptr, s1);

    gemm_kernel<<<500, 256, 0, stream>>>(s1, bc_idx, bc_w, W2g, bias2, S, normsq);
    pool_kernel<true><<<2500, 256, 0, stream>>>(S, normsq, gamma2, beta2, signal, out);
}

// Round 5
// 588.634 us; speedup vs baseline: 2.5300x; 1.1851x over previous
//
#include <hip/hip_runtime.h>

// Problem constants (fixed by reference)
#define NVV 10000    // vertices
#define NKSTEPS 80   // 2560 / 32
#define BN_INV 0.99950037468777316f

#define AS1 __attribute__((address_space(1)))
#define AS3 __attribute__((address_space(3)))

typedef float f32x4 __attribute__((ext_vector_type(4)));
typedef short short8 __attribute__((ext_vector_type(8)));
typedef unsigned short ushort;

// ---------------------------------------------------------------------------
// Split a f32 into bf16 (RNE) + f32 remainder (exact).
__device__ __forceinline__ ushort bsplit(float v, float& rem) {
    unsigned u = __float_as_uint(v);
    unsigned r = (u + 0x7fffu + ((u >> 16) & 1u)) & 0xffff0000u;
    rem = v - __uint_as_float(r);
    return (ushort)(r >> 16);
}

// blend 3 gathered float4 rows, split-3 to bf16 planes, store into sA frag layout
__device__ __forceinline__ void interp_store(ushort* __restrict__ sAp, int it,
                                             const float4& g0, const float4& g1, const float4& g2,
                                             float w0, float w1, float w2) {
    const int m = it >> 3, kq = it & 7;
    const float av[4] = {g0.x, g0.y, g0.z, g0.w};
    const float bv[4] = {g1.x, g1.y, g1.z, g1.w};
    const float cv[4] = {g2.x, g2.y, g2.z, g2.w};
    ushort h1[4], h2[4], h3[4];
    #pragma unroll
    for (int e = 0; e < 4; ++e) {
        const float vv = w0 * av[e] + w1 * bv[e] + w2 * cv[e];
        float r1, r2, r3;
        h1[e] = bsplit(vv, r1); h2[e] = bsplit(r1, r2); h3[e] = bsplit(r2, r3);
    }
    const int mt = m >> 4, mm = m & 15, qk = kq >> 1, hf = kq & 1;
    const int o0 = ((mt * 3 + 0) * 4 + qk) * 128 + mm * 8 + hf * 4;   // ushort units
    *(uint2*)(sAp + o0)        = make_uint2((unsigned)h1[0] | ((unsigned)h1[1] << 16),
                                            (unsigned)h1[2] | ((unsigned)h1[3] << 16));
    *(uint2*)(sAp + o0 + 512)  = make_uint2((unsigned)h2[0] | ((unsigned)h2[1] << 16),
                                            (unsigned)h2[2] | ((unsigned)h2[3] << 16));
    *(uint2*)(sAp + o0 + 1024) = make_uint2((unsigned)h3[0] | ((unsigned)h3[1] << 16),
                                            (unsigned)h3[2] | ((unsigned)h3[3] << 16));
}

// ---------------------------------------------------------------------------
// W global layout (per stage): [kstep 80][strip 4] chunks of 24576 B.
// Chunk: [nt 8][sp 3][q 4][lane16 16][kk 8] ushort — MFMA B-frag contiguous.
// Element (k,n): W[k][n] = T[t, r, (o+a)&7, c], k=(r,a,c), n=(o,t).
__global__ void build_w_kernel(const float* __restrict__ t1,
                               const float* __restrict__ t2,
                               ushort* __restrict__ W1g,
                               ushort* __restrict__ W2g) {
    const int k = blockIdx.x;       // 0..2559
    const int n = threadIdx.x;      // 0..511
    const float* T  = blockIdx.y ? t2 : t1;
    ushort*      Wg = blockIdx.y ? W2g : W1g;
    const int r = k >> 9, a = (k >> 6) & 7, c = k & 63;
    const int o = n >> 6, t = n & 63;
    const float w = T[((t * 5 + r) * 8 + ((o + a) & 7)) * 64 + c];
    float r1, r2, r3;
    const ushort h1 = bsplit(w, r1);
    const ushort h2 = bsplit(r1, r2);
    const ushort h3 = bsplit(r2, r3);
    const int kstep = k >> 5, kw = k & 31, q = kw >> 3, kk = kw & 7;
    const int strip = n >> 7, nl = n & 127, nt = nl >> 4, l16 = nl & 15;
    const size_t base = (size_t)(kstep * 4 + strip) * 12288;
    const int off = ((nt * 3 + 0) * 4 + q) * 128 + l16 * 8 + kk;
    Wg[base + off]        = h1;     // sp stride = 512 ushorts
    Wg[base + off + 512]  = h2;
    Wg[base + off + 1024] = h3;
}

// ---------------------------------------------------------------------------
// Split-3 bf16 MFMA GEMM. Block = 80 rows x 128 cols (one N-strip), K=2560.
// Grid 500: strip = b&3, mg = b>>2 — with round-robin block->XCD dispatch each
// XCD reads ONE W strip (1.97 MB, L2-resident).
// LDS: sW double-buffered (DMA covered by MFMA phase), sA single (2 barriers).
// 4 waves split N: wave wj owns n-tiles {2wj, 2wj+1}.
__global__ __launch_bounds__(256, 2)
void gemm_kernel(const float* __restrict__ src,      // gather source (rows of 64)
                 const int*   __restrict__ bc_idx,   // (V,R,A,3)
                 const float* __restrict__ bc_w,     // (V,R,A,3)
                 const ushort* __restrict__ Wg,
                 const float* __restrict__ bias,     // (64)
                 float*       __restrict__ S,        // (V,512)
                 float*       __restrict__ normsq) { // (V,8)
    __shared__ ushort sW[2][12288];   // 2 x 24576 B
    __shared__ ushort sA[7680];       // 15360 B
    // total static LDS = 64512 B  (<= 64 KiB workgroup cap)

    const int x = threadIdx.x;
    const int b = blockIdx.x;
    const int strip = b & 3;
    const int mg    = b >> 2;               // 0..124
    const int Mbase = mg * 80;
    const int wj  = x >> 6;
    const int l16 = x & 15;
    const int q   = (x & 63) >> 4;

    f32x4 d[5][2] = {};                     // 40 f32 accumulators

    const char* gW = (const char*)(Wg + (size_t)strip * 12288);
    // per-kstep stride = 4 strips * 24576 B

    // interp items: 640 = 80 rows x 8 k-quads; thread x handles x, x+256, x+512
    float4 ga[3], gb[3], gc[3];
    float  wa[3], wb[3], wc[3];

    // ---- prologue: DMA W(0) -> sW[0]; interp(0) -> sA ----
    {
        char* l = (char*)sW[0];
        #pragma unroll
        for (int j = 0; j < 6; ++j)
            __builtin_amdgcn_global_load_lds((AS1 const void*)(gW + (x + 256 * j) * 16),
                                             (AS3 void*)(l + (x + 256 * j) * 16), 16, 0, 0);
        #pragma unroll
        for (int s = 0; s < 3; ++s) {
            const int it = x + 256 * s;
            if (it < 640) {
                const int m = it >> 3, kq = it & 7;
                const int v = Mbase + m;
                const int*   ip = bc_idx + v * 120;      // ra = 0
                const float* wp = bc_w  + v * 120;
                const int c0 = kq * 4;                   // ks = 0
                const float4 g0 = *(const float4*)(src + (size_t)ip[0] * 64 + c0);
                const float4 g1 = *(const float4*)(src + (size_t)ip[1] * 64 + c0);
                const float4 g2 = *(const float4*)(src + (size_t)ip[2] * 64 + c0);
                interp_store(sA, it, g0, g1, g2, wp[0], wp[1], wp[2]);
            }
        }
    }
    __syncthreads();

    // ---- main loop: 2 barriers per kstep ----
    for (int ks = 0; ks < NKSTEPS; ++ks) {
        const int cur = ks & 1, nxt = cur ^ 1;
        const bool hn = (ks + 1 < NKSTEPS);

        // issue gathers(ks+1) into regs + DMA W(ks+1) -> sW[nxt]
        if (hn) {
            const int ksn = ks + 1;
            const int ra  = ksn >> 1;
            #pragma unroll
            for (int s = 0; s < 3; ++s) {
                const int it = x + 256 * s;
                if (it < 640) {
                    const int m = it >> 3, kq = it & 7;
                    const int v = Mbase + m;
                    const int*   ip = bc_idx + v * 120 + ra * 3;
                    const float* wp = bc_w  + v * 120 + ra * 3;
                    const int c0 = (ksn & 1) * 32 + kq * 4;
                    ga[s] = *(const float4*)(src + (size_t)ip[0] * 64 + c0);
                    gb[s] = *(const float4*)(src + (size_t)ip[1] * 64 + c0);
                    gc[s] = *(const float4*)(src + (size_t)ip[2] * 64 + c0);
                    wa[s] = wp[0]; wb[s] = wp[1]; wc[s] = wp[2];
                }
            }
            const char* g = gW + (size_t)(ks + 1) * (4 * 24576);
            char*       l = (char*)sW[nxt];
            #pragma unroll
            for (int j = 0; j < 6; ++j)
                __builtin_amdgcn_global_load_lds((AS1 const void*)(g + (x + 256 * j) * 16),
                                                 (AS3 void*)(l + (x + 256 * j) * 16), 16, 0, 0);
        }

        // MFMA on sW[cur] + sA: 6 split-products per (mt, nt)
        short8 bf[2][3];
        #pragma unroll
        for (int nt = 0; nt < 2; ++nt)
            #pragma unroll
            for (int sp = 0; sp < 3; ++sp)
                bf[nt][sp] = *(const short8*)(sW[cur] + (((2 * wj + nt) * 3 + sp) * 4 + q) * 128 + l16 * 8);
        #pragma unroll
        for (int mt = 0; mt < 5; ++mt) {
            const short8 a1 = *(const short8*)(sA + ((mt * 3 + 0) * 4 + q) * 128 + l16 * 8);
            const short8 a2 = *(const short8*)(sA + ((mt * 3 + 1) * 4 + q) * 128 + l16 * 8);
            const short8 a3 = *(const short8*)(sA + ((mt * 3 + 2) * 4 + q) * 128 + l16 * 8);
            #pragma unroll
            for (int nt = 0; nt < 2; ++nt) {
                d[mt][nt] = __builtin_amdgcn_mfma_f32_16x16x32_bf16(a1, bf[nt][0], d[mt][nt], 0, 0, 0);
                d[mt][nt] = __builtin_amdgcn_mfma_f32_16x16x32_bf16(a1, bf[nt][1], d[mt][nt], 0, 0, 0);
                d[mt][nt] = __builtin_amdgcn_mfma_f32_16x16x32_bf16(a2, bf[nt][0], d[mt][nt], 0, 0, 0);
                d[mt][nt] = __builtin_amdgcn_mfma_f32_16x16x32_bf16(a2, bf[nt][1], d[mt][nt], 0, 0, 0);
                d[mt][nt] = __builtin_amdgcn_mfma_f32_16x16x32_bf16(a3, bf[nt][0], d[mt][nt], 0, 0, 0);
                d[mt][nt] = __builtin_amdgcn_mfma_f32_16x16x32_bf16(a1, bf[nt][2], d[mt][nt], 0, 0, 0);
            }
        }

        __syncthreads();   // all waves done reading sA; gathers+DMA drained

        // blend + split-3 + store interp(ks+1) into sA
        if (hn) {
            #pragma unroll
            for (int s = 0; s < 3; ++s) {
                const int it = x + 256 * s;
                if (it < 640)
                    interp_store(sA, it, ga[s], gb[s], gc[s], wa[s], wb[s], wc[s]);
            }
        }
        __syncthreads();   // sA(ks+1) visible; no outstanding vmem here
    }

    // ---- epilogue: +bias, store S, norms^2 -> normsq (sN aliases sA) ----
    float* sN = (float*)sA;   // [wj 4][m 80]
    float bs[2];
    #pragma unroll
    for (int nt = 0; nt < 2; ++nt)
        bs[nt] = bias[(32 * wj + 16 * nt + l16) & 63];

    float p[5][4];
    #pragma unroll
    for (int mt = 0; mt < 5; ++mt)
        #pragma unroll
        for (int r = 0; r < 4; ++r) p[mt][r] = 0.0f;

    #pragma unroll
    for (int mt = 0; mt < 5; ++mt) {
        #pragma unroll
        for (int nt = 0; nt < 2; ++nt) {
            #pragma unroll
            for (int r = 0; r < 4; ++r) {
                const float val = d[mt][nt][r] + bs[nt];
                const int mglob = Mbase + mt * 16 + q * 4 + r;
                const int nglob = strip * 128 + wj * 32 + nt * 16 + l16;
                S[(size_t)mglob * 512 + nglob] = val;
                p[mt][r] += val * val;
            }
        }
    }
    #pragma unroll
    for (int mt = 0; mt < 5; ++mt)
        #pragma unroll
        for (int r = 0; r < 4; ++r) {
            float v = p[mt][r];
            v += __shfl_xor(v, 1, 64);
            v += __shfl_xor(v, 2, 64);
            v += __shfl_xor(v, 4, 64);
            v += __shfl_xor(v, 8, 64);
            p[mt][r] = v;
        }
    if (l16 == 0) {
        #pragma unroll
        for (int mt = 0; mt < 5; ++mt)
            #pragma unroll
            for (int r = 0; r < 4; ++r)
                sN[wj * 80 + mt * 16 + q * 4 + r] = p[mt][r];
    }
    __syncthreads();
    if (x < 80) {
        const int v = Mbase + x;
        // waves 0,1 -> o = strip*2 ; waves 2,3 -> o = strip*2+1
        normsq[(size_t)v * 8 + strip * 2]     = sN[0 * 80 + x] + sN[1 * 80 + x];
        normsq[(size_t)v * 8 + strip * 2 + 1] = sN[2 * 80 + x] + sN[3 * 80 + x];
    }
}

// ---------------------------------------------------------------------------
// Angular max-pool + BN (+residual) + ReLU. One thread per (v, t).
template<bool RES>
__global__ void pool_kernel(const float* __restrict__ S,
                            const float* __restrict__ normsq,
                            const float* __restrict__ gamma,
                            const float* __restrict__ beta,
                            const float* __restrict__ resid,
                            float*       __restrict__ dst) {
    const int gid = blockIdx.x * 256 + threadIdx.x;   // 640000 = 2500*256
    const int v = gid >> 6, t = gid & 63;
    const float* nv = normsq + (size_t)v * 8;
    float bv = nv[0];
    int   bj = 0;
    #pragma unroll
    for (int j = 1; j < 8; ++j) {
        const float tv = nv[j];
        if (tv > bv) { bv = tv; bj = j; }   // first-max tie-break (jnp.argmax)
    }
    const float val = S[(size_t)v * 512 + bj * 64 + t];
    float r = gamma[t] * (val * BN_INV) + beta[t];
    if (RES) r += resid[(size_t)v * 64 + t];
    dst[(size_t)v * 64 + t] = fmaxf(r, 0.0f);
}

// ---------------------------------------------------------------------------
extern "C" void kernel_launch(void* const* d_in, const int* in_sizes, int n_in,
                              void* d_out, int out_size, void* d_ws, size_t ws_size,
                              hipStream_t stream) {
    const float* signal = (const float*)d_in[0];
    const float* bc_w   = (const float*)d_in[1];
    const float* t1     = (const float*)d_in[2];
    const float* bias1  = (const float*)d_in[3];
    const float* gamma1 = (const float*)d_in[4];
    const float* beta1  = (const float*)d_in[5];
    const float* t2     = (const float*)d_in[6];
    const float* bias2  = (const float*)d_in[7];
    const float* gamma2 = (const float*)d_in[8];
    const float* beta2  = (const float*)d_in[9];
    const int*   bc_idx = (const int*)d_in[10];

    // ws: W1g 7.86 MB | W2g 7.86 MB | S 20.48 MB | normsq 320 KB | s1 2.56 MB
    ushort* W1g = (ushort*)d_ws;
    ushort* W2g = W1g + (size_t)80 * 4 * 12288;
    float* S      = (float*)(W2g + (size_t)80 * 4 * 12288);
    float* normsq = S + (size_t)NVV * 512;
    float* s1     = normsq + (size_t)NVV * 8;
    float* out    = (float*)d_out;

    build_w_kernel<<<dim3(2560, 2), 512, 0, stream>>>(t1, t2, W1g, W2g);

    gemm_kernel<<<500, 256, 0, stream>>>(signal, bc_idx, bc_w, W1g, bias1, S, normsq);
    pool_kernel<false><<<2500, 256, 0, stream>>>(S, normsq, gamma1, beta1, nullptr, s1);

    gemm_kernel<<<500, 256, 0, stream>>>(s1, bc_idx, bc_w, W2g, bias2, S, normsq);
    pool_kernel<true><<<2500, 256, 0, stream>>>(S, normsq, gamma2, beta2, signal, out);
}

// Round 6
// 396.773 us; speedup vs baseline: 3.7534x; 1.4836x over previous
//
#include <hip/hip_runtime.h>

// Problem constants (fixed by reference)
#define NVV 10000    // vertices
#define NKSTEPS 80   // 2560 / 32
#define BN_INV 0.99950037468777316f

#define AS1 __attribute__((address_space(1)))
#define AS3 __attribute__((address_space(3)))

typedef float f32x4 __attribute__((ext_vector_type(4)));
typedef short short8 __attribute__((ext_vector_type(8)));
typedef unsigned short ushort;

// ---------------------------------------------------------------------------
// Split a f32 into bf16 (RNE) + f32 remainder (exact).
__device__ __forceinline__ ushort bsplit(float v, float& rem) {
    unsigned u = __float_as_uint(v);
    unsigned r = (u + 0x7fffu + ((u >> 16) & 1u)) & 0xffff0000u;
    rem = v - __uint_as_float(r);
    return (ushort)(r >> 16);
}

// blend 3 gathered float4 rows, split-3 to bf16 planes, store into frag layout
// (works for an LDS or global destination pointer).
__device__ __forceinline__ void interp_store(ushort* __restrict__ dstp, int it,
                                             const float4& g0, const float4& g1, const float4& g2,
                                             float w0, float w1, float w2) {
    const int m = it >> 3, kq = it & 7;
    const float av[4] = {g0.x, g0.y, g0.z, g0.w};
    const float bv[4] = {g1.x, g1.y, g1.z, g1.w};
    const float cv[4] = {g2.x, g2.y, g2.z, g2.w};
    ushort h1[4], h2[4], h3[4];
    #pragma unroll
    for (int e = 0; e < 4; ++e) {
        const float vv = w0 * av[e] + w1 * bv[e] + w2 * cv[e];
        float r1, r2, r3;
        h1[e] = bsplit(vv, r1); h2[e] = bsplit(r1, r2); h3[e] = bsplit(r2, r3);
    }
    const int mt = m >> 4, mm = m & 15, qk = kq >> 1, hf = kq & 1;
    const int o0 = ((mt * 3 + 0) * 4 + qk) * 128 + mm * 8 + hf * 4;   // ushort units
    *(uint2*)(dstp + o0)        = make_uint2((unsigned)h1[0] | ((unsigned)h1[1] << 16),
                                             (unsigned)h1[2] | ((unsigned)h1[3] << 16));
    *(uint2*)(dstp + o0 + 512)  = make_uint2((unsigned)h2[0] | ((unsigned)h2[1] << 16),
                                             (unsigned)h2[2] | ((unsigned)h2[3] << 16));
    *(uint2*)(dstp + o0 + 1024) = make_uint2((unsigned)h3[0] | ((unsigned)h3[1] << 16),
                                             (unsigned)h3[2] | ((unsigned)h3[3] << 16));
}

// ---------------------------------------------------------------------------
// W global layout (per stage): [kstep 80][strip 4] chunks of 16384 B.
// Chunk: [nt 8][sp 2][q 4][lane16 16][kk 8] ushort — MFMA B-frag contiguous.
// w = w1 + w2 (2 RNE planes; residual <= 2^-18 relative).
__global__ void build_w_kernel(const float* __restrict__ t1,
                               const float* __restrict__ t2,
                               ushort* __restrict__ W1g,
                               ushort* __restrict__ W2g) {
    const int k = blockIdx.x;       // 0..2559
    const int n = threadIdx.x;      // 0..511
    const float* T  = blockIdx.y ? t2 : t1;
    ushort*      Wg = blockIdx.y ? W2g : W1g;
    const int r = k >> 9, a = (k >> 6) & 7, c = k & 63;
    const int o = n >> 6, t = n & 63;
    const float w = T[((t * 5 + r) * 8 + ((o + a) & 7)) * 64 + c];
    float r1, r2;
    const ushort h1 = bsplit(w, r1);
    const ushort h2 = bsplit(r1, r2);
    const int kstep = k >> 5, kw = k & 31, q = kw >> 3, kk = kw & 7;
    const int strip = n >> 7, nl = n & 127, nt = nl >> 4, l16 = nl & 15;
    const size_t base = (size_t)(kstep * 4 + strip) * 8192;
    const int off = ((nt * 2 + 0) * 4 + q) * 128 + l16 * 8 + kk;
    Wg[base + off]       = h1;      // sp stride = 512 ushorts
    Wg[base + off + 512] = h2;
}

// ---------------------------------------------------------------------------
// Materialize interp (gather+blend) as 3 exact bf16 split planes, in the
// GEMM A-frag layout. One block per (mg-local, kstep) chunk of 15360 B:
// chunk = [mt 5][sp 3][qk 4][mm 16][kk 8] ushort.
__global__ void interp_kernel(const float* __restrict__ src,
                              const int*   __restrict__ bc_idx,
                              const float* __restrict__ bc_w,
                              ushort*      __restrict__ Ag,
                              int mg0) {
    const int cid = blockIdx.x;            // local chunk id
    const int mgl = cid / NKSTEPS;
    const int ks  = cid % NKSTEPS;
    const int mg  = mg0 + mgl;
    const int x   = threadIdx.x;
    ushort* chunk = Ag + (size_t)cid * 7680;
    const int ra = ks >> 1;
    #pragma unroll
    for (int s = 0; s < 3; ++s) {
        const int it = x + 256 * s;        // 640 items = 80 rows x 8 k-quads
        if (it < 640) {
            const int m = it >> 3, kq = it & 7;
            const int v = mg * 80 + m;
            const int*   ip = bc_idx + v * 120 + ra * 3;
            const float* wp = bc_w  + v * 120 + ra * 3;
            const int c0 = (ks & 1) * 32 + kq * 4;
            const float4 g0 = *(const float4*)(src + (size_t)ip[0] * 64 + c0);
            const float4 g1 = *(const float4*)(src + (size_t)ip[1] * 64 + c0);
            const float4 g2 = *(const float4*)(src + (size_t)ip[2] * 64 + c0);
            interp_store(chunk, it, g0, g1, g2, wp[0], wp[1], wp[2]);
        }
    }
}

// ---------------------------------------------------------------------------
// 5-product split MFMA GEMM, fully double-buffered, ONE barrier per kstep.
// Block = 80 rows x 128 cols (one N-strip). strip = b&3 (XCD-local W strip;
// the 4 strip-blocks of one mg dispatch together -> shared A chunk hits LLC).
// Pure DMA + MFMA: no interp VALU in the K-loop.
__global__ __launch_bounds__(256, 2)
void gemm_kernel(const ushort* __restrict__ Ag,
                 const ushort* __restrict__ Wg,
                 const float* __restrict__ bias,     // (64)
                 float*       __restrict__ S,        // (V,512)
                 float*       __restrict__ normsq,   // (V,8)
                 int mg0) {
    __shared__ ushort sW[2][8192];    // 2 x 16384 B
    __shared__ ushort sA[2][7680];    // 2 x 15360 B   total 63488 B
    const int x = threadIdx.x;
    const int b = blockIdx.x;
    const int strip = b & 3;
    const int mgl   = b >> 2;
    const int mg    = mg0 + mgl;
    const int Mbase = mg * 80;
    const int wj  = x >> 6;
    const int l16 = x & 15;
    const int q   = (x & 63) >> 4;

    f32x4 d[5][2] = {};               // 40 f32 accumulators

    // ---- prologue: DMA W(0), A(0) into buffer 0 ----
    {
        const char* gw = (const char*)Wg + (size_t)(0 * 4 + strip) * 16384;
        char*       lw = (char*)sW[0];
        #pragma unroll
        for (int j = 0; j < 4; ++j)
            __builtin_amdgcn_global_load_lds((AS1 const void*)(gw + (x + 256 * j) * 16),
                                             (AS3 void*)(lw + (x + 256 * j) * 16), 16, 0, 0);
        const char* ga = (const char*)Ag + ((size_t)mgl * NKSTEPS + 0) * 15360;
        char*       la = (char*)sA[0];
        #pragma unroll
        for (int j = 0; j < 4; ++j) {
            const int it = x + 256 * j;
            if (it < 960)
                __builtin_amdgcn_global_load_lds((AS1 const void*)(ga + it * 16),
                                                 (AS3 void*)(la + it * 16), 16, 0, 0);
        }
    }
    __syncthreads();

    // ---- main loop: 1 barrier per kstep ----
    for (int ks = 0; ks < NKSTEPS; ++ks) {
        const int cur = ks & 1, nxt = cur ^ 1;
        if (ks + 1 < NKSTEPS) {
            const char* gw = (const char*)Wg + (size_t)((ks + 1) * 4 + strip) * 16384;
            char*       lw = (char*)sW[nxt];
            #pragma unroll
            for (int j = 0; j < 4; ++j)
                __builtin_amdgcn_global_load_lds((AS1 const void*)(gw + (x + 256 * j) * 16),
                                                 (AS3 void*)(lw + (x + 256 * j) * 16), 16, 0, 0);
            const char* ga = (const char*)Ag + ((size_t)mgl * NKSTEPS + (ks + 1)) * 15360;
            char*       la = (char*)sA[nxt];
            #pragma unroll
            for (int j = 0; j < 4; ++j) {
                const int it = x + 256 * j;
                if (it < 960)
                    __builtin_amdgcn_global_load_lds((AS1 const void*)(ga + it * 16),
                                                     (AS3 void*)(la + it * 16), 16, 0, 0);
            }
        }

        // MFMA: 5 products {a1w1, a1w2, a2w1, a2w2, a3w1} per (mt, nt)
        short8 w1f[2], w2f[2];
        #pragma unroll
        for (int nt = 0; nt < 2; ++nt) {
            const int ntg = 2 * wj + nt;
            w1f[nt] = *(const short8*)(sW[cur] + ((ntg * 2 + 0) * 4 + q) * 128 + l16 * 8);
            w2f[nt] = *(const short8*)(sW[cur] + ((ntg * 2 + 1) * 4 + q) * 128 + l16 * 8);
        }
        #pragma unroll
        for (int mt = 0; mt < 5; ++mt) {
            const short8 a1 = *(const short8*)(sA[cur] + ((mt * 3 + 0) * 4 + q) * 128 + l16 * 8);
            const short8 a2 = *(const short8*)(sA[cur] + ((mt * 3 + 1) * 4 + q) * 128 + l16 * 8);
            const short8 a3 = *(const short8*)(sA[cur] + ((mt * 3 + 2) * 4 + q) * 128 + l16 * 8);
            #pragma unroll
            for (int nt = 0; nt < 2; ++nt) {
                d[mt][nt] = __builtin_amdgcn_mfma_f32_16x16x32_bf16(a1, w1f[nt], d[mt][nt], 0, 0, 0);
                d[mt][nt] = __builtin_amdgcn_mfma_f32_16x16x32_bf16(a1, w2f[nt], d[mt][nt], 0, 0, 0);
                d[mt][nt] = __builtin_amdgcn_mfma_f32_16x16x32_bf16(a2, w1f[nt], d[mt][nt], 0, 0, 0);
                d[mt][nt] = __builtin_amdgcn_mfma_f32_16x16x32_bf16(a2, w2f[nt], d[mt][nt], 0, 0, 0);
                d[mt][nt] = __builtin_amdgcn_mfma_f32_16x16x32_bf16(a3, w1f[nt], d[mt][nt], 0, 0, 0);
            }
        }
        __syncthreads();   // drains DMA(ks+1) (covered by MFMA phase) + closes reads
    }

    // ---- epilogue: +bias, store S, norms^2 -> normsq (sN aliases sA) ----
    float* sN = (float*)sA;   // [wj 4][m 80]
    float bs[2];
    #pragma unroll
    for (int nt = 0; nt < 2; ++nt)
        bs[nt] = bias[(32 * wj + 16 * nt + l16) & 63];

    float p[5][4];
    #pragma unroll
    for (int mt = 0; mt < 5; ++mt)
        #pragma unroll
        for (int r = 0; r < 4; ++r) p[mt][r] = 0.0f;

    #pragma unroll
    for (int mt = 0; mt < 5; ++mt) {
        #pragma unroll
        for (int nt = 0; nt < 2; ++nt) {
            #pragma unroll
            for (int r = 0; r < 4; ++r) {
                const float val = d[mt][nt][r] + bs[nt];
                const int mglob = Mbase + mt * 16 + q * 4 + r;
                const int nglob = strip * 128 + wj * 32 + nt * 16 + l16;
                S[(size_t)mglob * 512 + nglob] = val;
                p[mt][r] += val * val;
            }
        }
    }
    #pragma unroll
    for (int mt = 0; mt < 5; ++mt)
        #pragma unroll
        for (int r = 0; r < 4; ++r) {
            float v = p[mt][r];
            v += __shfl_xor(v, 1, 64);
            v += __shfl_xor(v, 2, 64);
            v += __shfl_xor(v, 4, 64);
            v += __shfl_xor(v, 8, 64);
            p[mt][r] = v;
        }
    if (l16 == 0) {
        #pragma unroll
        for (int mt = 0; mt < 5; ++mt)
            #pragma unroll
            for (int r = 0; r < 4; ++r)
                sN[wj * 80 + mt * 16 + q * 4 + r] = p[mt][r];
    }
    __syncthreads();
    if (x < 80) {
        const int v = Mbase + x;
        normsq[(size_t)v * 8 + strip * 2]     = sN[0 * 80 + x] + sN[1 * 80 + x];
        normsq[(size_t)v * 8 + strip * 2 + 1] = sN[2 * 80 + x] + sN[3 * 80 + x];
    }
}

// ---------------------------------------------------------------------------
// Angular max-pool + BN (+residual) + ReLU. One thread per (v, t).
template<bool RES>
__global__ void pool_kernel(const float* __restrict__ S,
                            const float* __restrict__ normsq,
                            const float* __restrict__ gamma,
                            const float* __restrict__ beta,
                            const float* __restrict__ resid,
                            float*       __restrict__ dst) {
    const int gid = blockIdx.x * 256 + threadIdx.x;   // 640000 = 2500*256
    const int v = gid >> 6, t = gid & 63;
    const float* nv = normsq + (size_t)v * 8;
    float bv = nv[0];
    int   bj = 0;
    #pragma unroll
    for (int j = 1; j < 8; ++j) {
        const float tv = nv[j];
        if (tv > bv) { bv = tv; bj = j; }   // first-max tie-break (jnp.argmax)
    }
    const float val = S[(size_t)v * 512 + bj * 64 + t];
    float r = gamma[t] * (val * BN_INV) + beta[t];
    if (RES) r += resid[(size_t)v * 64 + t];
    dst[(size_t)v * 64 + t] = fmaxf(r, 0.0f);
}

// ---------------------------------------------------------------------------
extern "C" void kernel_launch(void* const* d_in, const int* in_sizes, int n_in,
                              void* d_out, int out_size, void* d_ws, size_t ws_size,
                              hipStream_t stream) {
    const float* signal = (const float*)d_in[0];
    const float* bc_w   = (const float*)d_in[1];
    const float* t1     = (const float*)d_in[2];
    const float* bias1  = (const float*)d_in[3];
    const float* gamma1 = (const float*)d_in[4];
    const float* beta1  = (const float*)d_in[5];
    const float* t2     = (const float*)d_in[6];
    const float* bias2  = (const float*)d_in[7];
    const float* gamma2 = (const float*)d_in[8];
    const float* beta2  = (const float*)d_in[9];
    const int*   bc_idx = (const int*)d_in[10];

    // ws: W1g 5.24 MB | W2g 5.24 MB | S 20.48 MB | normsq 0.32 MB | s1 2.56 MB | Ag (rest)
    const size_t WSTG = (size_t)NKSTEPS * 4 * 8192;       // ushorts per stage W
    ushort* W1g = (ushort*)d_ws;
    ushort* W2g = W1g + WSTG;
    float* S      = (float*)(W2g + WSTG);
    float* normsq = S + (size_t)NVV * 512;
    float* s1     = normsq + (size_t)NVV * 8;
    ushort* Ag    = (ushort*)(s1 + (size_t)NVV * 64);
    float* out    = (float*)d_out;

    // pass-chunk the materialized interp to fit ws_size (full A = 153.6 MB)
    const size_t used  = (size_t)((char*)Ag - (char*)d_ws);
    const size_t avail = ws_size > used ? ws_size - used : 0;
    int P = (int)(avail / ((size_t)NKSTEPS * 15360));     // mgs per pass
    if (P > 125) P = 125;
    if (P < 1)  P = 1;

    build_w_kernel<<<dim3(2560, 2), 512, 0, stream>>>(t1, t2, W1g, W2g);

    // stage 1
    for (int mg0 = 0; mg0 < 125; mg0 += P) {
        const int Pp = (125 - mg0 < P) ? (125 - mg0) : P;
        interp_kernel<<<Pp * NKSTEPS, 256, 0, stream>>>(signal, bc_idx, bc_w, Ag, mg0);
        gemm_kernel<<<Pp * 4, 256, 0, stream>>>(Ag, W1g, bias1, S, normsq, mg0);
    }
    pool_kernel<false><<<2500, 256, 0, stream>>>(S, normsq, gamma1, beta1, nullptr, s1);

    // stage 2
    for (int mg0 = 0; mg0 < 125; mg0 += P) {
        const int Pp = (125 - mg0 < P) ? (125 - mg0) : P;
        interp_kernel<<<Pp * NKSTEPS, 256, 0, stream>>>(s1, bc_idx, bc_w, Ag, mg0);
        gemm_kernel<<<Pp * 4, 256, 0, stream>>>(Ag, W2g, bias2, S, normsq, mg0);
    }
    pool_kernel<true><<<2500, 256, 0, stream>>>(S, normsq, gamma2, beta2, signal, out);
}

// Round 7
// 347.750 us; speedup vs baseline: 4.2825x; 1.1410x over previous
//
#include <hip/hip_runtime.h>

// Problem constants (fixed by reference)
#define NVV 10000    // vertices
#define NKSTEPS 80   // 2560 / 32
#define BN_INV 0.99950037468777316f

#define AS1 __attribute__((address_space(1)))
#define AS3 __attribute__((address_space(3)))

typedef float f32x4 __attribute__((ext_vector_type(4)));
typedef short short8 __attribute__((ext_vector_type(8)));
typedef unsigned short ushort;

// A chunk: [mt 5][sp 2][qk 4][mm 16][kk 8] ushort = 5120 ushorts = 10240 B
#define ACH_USH 5120
#define ACH_B   10240
// W chunk (per kstep,strip): [nt 8][sp 2][q 4][l16 16][kk 8] = 8192 ushorts = 16384 B
#define WCH_B   16384

// ---------------------------------------------------------------------------
// Split a f32 into bf16 (RNE) + f32 remainder (exact).
__device__ __forceinline__ ushort bsplit(float v, float& rem) {
    unsigned u = __float_as_uint(v);
    unsigned r = (u + 0x7fffu + ((u >> 16) & 1u)) & 0xffff0000u;
    rem = v - __uint_as_float(r);
    return (ushort)(r >> 16);
}

// blend 3 gathered float4 rows, split-2 (RNE+RNE) to bf16 planes, store frag layout
__device__ __forceinline__ void interp_store2(ushort* __restrict__ dstp, int it,
                                              const float4& g0, const float4& g1, const float4& g2,
                                              float w0, float w1, float w2) {
    const int m = it >> 3, kq = it & 7;
    const float av[4] = {g0.x, g0.y, g0.z, g0.w};
    const float bv[4] = {g1.x, g1.y, g1.z, g1.w};
    const float cv[4] = {g2.x, g2.y, g2.z, g2.w};
    ushort h1[4], h2[4];
    #pragma unroll
    for (int e = 0; e < 4; ++e) {
        const float vv = w0 * av[e] + w1 * bv[e] + w2 * cv[e];
        float r1, r2;
        h1[e] = bsplit(vv, r1); h2[e] = bsplit(r1, r2);
    }
    const int mt = m >> 4, mm = m & 15, qk = kq >> 1, hf = kq & 1;
    const int o0 = ((mt * 2 + 0) * 4 + qk) * 128 + mm * 8 + hf * 4;   // ushort units
    *(uint2*)(dstp + o0)       = make_uint2((unsigned)h1[0] | ((unsigned)h1[1] << 16),
                                            (unsigned)h1[2] | ((unsigned)h1[3] << 16));
    *(uint2*)(dstp + o0 + 512) = make_uint2((unsigned)h2[0] | ((unsigned)h2[1] << 16),
                                            (unsigned)h2[2] | ((unsigned)h2[3] << 16));
}

// ---------------------------------------------------------------------------
// W global layout (per stage): [kstep 80][strip 4] chunks of 16384 B.
// w = w1 + w2 (2 RNE planes; residual <= 2^-18 relative).
__global__ void build_w_kernel(const float* __restrict__ t1,
                               const float* __restrict__ t2,
                               ushort* __restrict__ W1g,
                               ushort* __restrict__ W2g) {
    const int k = blockIdx.x;       // 0..2559
    const int n = threadIdx.x;      // 0..511
    const float* T  = blockIdx.y ? t2 : t1;
    ushort*      Wg = blockIdx.y ? W2g : W1g;
    const int r = k >> 9, a = (k >> 6) & 7, c = k & 63;
    const int o = n >> 6, t = n & 63;
    const float w = T[((t * 5 + r) * 8 + ((o + a) & 7)) * 64 + c];
    float r1, r2;
    const ushort h1 = bsplit(w, r1);
    const ushort h2 = bsplit(r1, r2);
    const int kstep = k >> 5, kw = k & 31, q = kw >> 3, kk = kw & 7;
    const int strip = n >> 7, nl = n & 127, nt = nl >> 4, l16 = nl & 15;
    const size_t base = (size_t)(kstep * 4 + strip) * 8192;
    const int off = ((nt * 2 + 0) * 4 + q) * 128 + l16 * 8 + kk;
    Wg[base + off]       = h1;      // sp stride = 512 ushorts
    Wg[base + off + 512] = h2;
}

// ---------------------------------------------------------------------------
// Materialize interp (gather+blend) as 2 RNE bf16 split planes, A-frag layout.
// One block per (mg-local, kstep) chunk of 10240 B.
__global__ void interp_kernel(const float* __restrict__ src,
                              const int*   __restrict__ bc_idx,
                              const float* __restrict__ bc_w,
                              ushort*      __restrict__ Ag,
                              int mg0) {
    const int cid = blockIdx.x;            // pass-local chunk id
    const int mgl = cid / NKSTEPS;
    const int ks  = cid % NKSTEPS;
    const int mg  = mg0 + mgl;
    const int x   = threadIdx.x;
    ushort* chunk = Ag + (size_t)cid * ACH_USH;
    const int ra = ks >> 1;
    #pragma unroll
    for (int s = 0; s < 3; ++s) {
        const int it = x + 256 * s;        // 640 items = 80 rows x 8 k-quads
        if (it < 640) {
            const int m = it >> 3, kq = it & 7;
            const int v = mg * 80 + m;
            const int*   ip = bc_idx + v * 120 + ra * 3;
            const float* wp = bc_w  + v * 120 + ra * 3;
            const int c0 = (ks & 1) * 32 + kq * 4;
            const float4 g0 = *(const float4*)(src + (size_t)ip[0] * 64 + c0);
            const float4 g1 = *(const float4*)(src + (size_t)ip[1] * 64 + c0);
            const float4 g2 = *(const float4*)(src + (size_t)ip[2] * 64 + c0);
            interp_store2(chunk, it, g0, g1, g2, wp[0], wp[1], wp[2]);
        }
    }
}

// ---------------------------------------------------------------------------
// 4-product split MFMA GEMM, fully double-buffered, ONE barrier per kstep.
// Block = 80 rows x 128 cols. XCD-pinned mapping: xcd = b&7 owns mgs
// [xcd*mpx, xcd*mpx+mpx) — all 4 strip-blocks of an mg on ONE XCD, so each
// A chunk fills exactly one L2. Pure DMA + MFMA in the K-loop.
__global__ __launch_bounds__(256, 3)
void gemm_kernel(const ushort* __restrict__ Ag,
                 const ushort* __restrict__ Wg,
                 const float* __restrict__ bias,     // (64)
                 float*       __restrict__ S,        // (V,512)
                 float*       __restrict__ normsq,   // (V,8)
                 int mg0, int Pp, int mpx) {
    __shared__ ushort sW[2][8192];    // 2 x 16384 B
    __shared__ ushort sA[2][ACH_USH]; // 2 x 10240 B   total 53248 B
    const int x = threadIdx.x;
    const int b = blockIdx.x;
    const int xcd  = b & 7;
    const int rest = b >> 3;
    const int strip = rest & 3;
    const int mgl_l = rest >> 2;
    const int mg_local = xcd * mpx + mgl_l;
    if (mg_local >= Pp) return;
    const int mg    = mg0 + mg_local;
    const int Mbase = mg * 80;
    const int wj  = x >> 6;
    const int l16 = x & 15;
    const int q   = (x & 63) >> 4;

    f32x4 d[5][2] = {};               // 40 f32 accumulators

    const char* gWb = (const char*)Wg;
    const char* gAb = (const char*)Ag + (size_t)mg_local * NKSTEPS * ACH_B;

    // ---- prologue: DMA W(0), A(0) into buffer 0 ----
    {
        const char* gw = gWb + (size_t)(0 * 4 + strip) * WCH_B;
        char*       lw = (char*)sW[0];
        #pragma unroll
        for (int j = 0; j < 4; ++j)
            __builtin_amdgcn_global_load_lds((AS1 const void*)(gw + (x + 256 * j) * 16),
                                             (AS3 void*)(lw + (x + 256 * j) * 16), 16, 0, 0);
        const char* ga = gAb;
        char*       la = (char*)sA[0];
        #pragma unroll
        for (int j = 0; j < 3; ++j) {
            const int it = x + 256 * j;
            if (it < 640)
                __builtin_amdgcn_global_load_lds((AS1 const void*)(ga + it * 16),
                                                 (AS3 void*)(la + it * 16), 16, 0, 0);
        }
    }
    __syncthreads();

    // ---- main loop: 1 barrier per kstep ----
    for (int ks = 0; ks < NKSTEPS; ++ks) {
        const int cur = ks & 1, nxt = cur ^ 1;
        if (ks + 1 < NKSTEPS) {
            const char* gw = gWb + (size_t)((ks + 1) * 4 + strip) * WCH_B;
            char*       lw = (char*)sW[nxt];
            #pragma unroll
            for (int j = 0; j < 4; ++j)
                __builtin_amdgcn_global_load_lds((AS1 const void*)(gw + (x + 256 * j) * 16),
                                                 (AS3 void*)(lw + (x + 256 * j) * 16), 16, 0, 0);
            const char* ga = gAb + (size_t)(ks + 1) * ACH_B;
            char*       la = (char*)sA[nxt];
            #pragma unroll
            for (int j = 0; j < 3; ++j) {
                const int it = x + 256 * j;
                if (it < 640)
                    __builtin_amdgcn_global_load_lds((AS1 const void*)(ga + it * 16),
                                                     (AS3 void*)(la + it * 16), 16, 0, 0);
            }
        }

        // MFMA: 4 products {a1w1, a1w2, a2w1, a2w2} per (mt, nt)
        short8 w1f[2], w2f[2];
        #pragma unroll
        for (int nt = 0; nt < 2; ++nt) {
            const int ntg = 2 * wj + nt;
            w1f[nt] = *(const short8*)(sW[cur] + ((ntg * 2 + 0) * 4 + q) * 128 + l16 * 8);
            w2f[nt] = *(const short8*)(sW[cur] + ((ntg * 2 + 1) * 4 + q) * 128 + l16 * 8);
        }
        #pragma unroll
        for (int mt = 0; mt < 5; ++mt) {
            const short8 a1 = *(const short8*)(sA[cur] + ((mt * 2 + 0) * 4 + q) * 128 + l16 * 8);
            const short8 a2 = *(const short8*)(sA[cur] + ((mt * 2 + 1) * 4 + q) * 128 + l16 * 8);
            #pragma unroll
            for (int nt = 0; nt < 2; ++nt) {
                d[mt][nt] = __builtin_amdgcn_mfma_f32_16x16x32_bf16(a1, w1f[nt], d[mt][nt], 0, 0, 0);
                d[mt][nt] = __builtin_amdgcn_mfma_f32_16x16x32_bf16(a1, w2f[nt], d[mt][nt], 0, 0, 0);
                d[mt][nt] = __builtin_amdgcn_mfma_f32_16x16x32_bf16(a2, w1f[nt], d[mt][nt], 0, 0, 0);
                d[mt][nt] = __builtin_amdgcn_mfma_f32_16x16x32_bf16(a2, w2f[nt], d[mt][nt], 0, 0, 0);
            }
        }
        __syncthreads();   // drains DMA(ks+1) (covered by MFMA phase) + closes reads
    }

    // ---- epilogue: +bias, store S, norms^2 -> normsq (sN aliases sA) ----
    float* sN = (float*)sA;   // [wj 4][m 80]
    float bs[2];
    #pragma unroll
    for (int nt = 0; nt < 2; ++nt)
        bs[nt] = bias[(32 * wj + 16 * nt + l16) & 63];

    float p[5][4];
    #pragma unroll
    for (int mt = 0; mt < 5; ++mt)
        #pragma unroll
        for (int r = 0; r < 4; ++r) p[mt][r] = 0.0f;

    #pragma unroll
    for (int mt = 0; mt < 5; ++mt) {
        #pragma unroll
        for (int nt = 0; nt < 2; ++nt) {
            #pragma unroll
            for (int r = 0; r < 4; ++r) {
                const float val = d[mt][nt][r] + bs[nt];
                const int mglob = Mbase + mt * 16 + q * 4 + r;
                const int nglob = strip * 128 + wj * 32 + nt * 16 + l16;
                S[(size_t)mglob * 512 + nglob] = val;
                p[mt][r] += val * val;
            }
        }
    }
    #pragma unroll
    for (int mt = 0; mt < 5; ++mt)
        #pragma unroll
        for (int r = 0; r < 4; ++r) {
            float v = p[mt][r];
            v += __shfl_xor(v, 1, 64);
            v += __shfl_xor(v, 2, 64);
            v += __shfl_xor(v, 4, 64);
            v += __shfl_xor(v, 8, 64);
            p[mt][r] = v;
        }
    if (l16 == 0) {
        #pragma unroll
        for (int mt = 0; mt < 5; ++mt)
            #pragma unroll
            for (int r = 0; r < 4; ++r)
                sN[wj * 80 + mt * 16 + q * 4 + r] = p[mt][r];
    }
    __syncthreads();
    if (x < 80) {
        const int v = Mbase + x;
        normsq[(size_t)v * 8 + strip * 2]     = sN[0 * 80 + x] + sN[1 * 80 + x];
        normsq[(size_t)v * 8 + strip * 2 + 1] = sN[2 * 80 + x] + sN[3 * 80 + x];
    }
}

// ---------------------------------------------------------------------------
// Angular max-pool + BN (+residual) + ReLU. One thread per (v, t).
template<bool RES>
__global__ void pool_kernel(const float* __restrict__ S,
                            const float* __restrict__ normsq,
                            const float* __restrict__ gamma,
                            const float* __restrict__ beta,
                            const float* __restrict__ resid,
                            float*       __restrict__ dst) {
    const int gid = blockIdx.x * 256 + threadIdx.x;   // 640000 = 2500*256
    const int v = gid >> 6, t = gid & 63;
    const float* nv = normsq + (size_t)v * 8;
    float bv = nv[0];
    int   bj = 0;
    #pragma unroll
    for (int j = 1; j < 8; ++j) {
        const float tv = nv[j];
        if (tv > bv) { bv = tv; bj = j; }   // first-max tie-break (jnp.argmax)
    }
    const float val = S[(size_t)v * 512 + bj * 64 + t];
    float r = gamma[t] * (val * BN_INV) + beta[t];
    if (RES) r += resid[(size_t)v * 64 + t];
    dst[(size_t)v * 64 + t] = fmaxf(r, 0.0f);
}

// ---------------------------------------------------------------------------
extern "C" void kernel_launch(void* const* d_in, const int* in_sizes, int n_in,
                              void* d_out, int out_size, void* d_ws, size_t ws_size,
                              hipStream_t stream) {
    const float* signal = (const float*)d_in[0];
    const float* bc_w   = (const float*)d_in[1];
    const float* t1     = (const float*)d_in[2];
    const float* bias1  = (const float*)d_in[3];
    const float* gamma1 = (const float*)d_in[4];
    const float* beta1  = (const float*)d_in[5];
    const float* t2     = (const float*)d_in[6];
    const float* bias2  = (const float*)d_in[7];
    const float* gamma2 = (const float*)d_in[8];
    const float* beta2  = (const float*)d_in[9];
    const int*   bc_idx = (const int*)d_in[10];

    // ws: W1g 5.24 MB | W2g 5.24 MB | S 20.48 MB | normsq 0.32 MB | s1 2.56 MB | Ag (rest)
    const size_t WSTG = (size_t)NKSTEPS * 4 * 8192;       // ushorts per stage W
    ushort* W1g = (ushort*)d_ws;
    ushort* W2g = W1g + WSTG;
    float* S      = (float*)(W2g + WSTG);
    float* normsq = S + (size_t)NVV * 512;
    float* s1     = normsq + (size_t)NVV * 8;
    ushort* Ag    = (ushort*)(s1 + (size_t)NVV * 64);
    float* out    = (float*)d_out;

    // pass-chunk the materialized interp to fit ws_size (full A = 102.4 MB)
    const size_t used  = (size_t)((char*)Ag - (char*)d_ws);
    const size_t avail = ws_size > used ? ws_size - used : 0;
    int P = (int)(avail / ((size_t)NKSTEPS * ACH_B));     // mgs per pass
    if (P > 125) P = 125;
    if (P < 1)  P = 1;

    build_w_kernel<<<dim3(2560, 2), 512, 0, stream>>>(t1, t2, W1g, W2g);

    // stage 1
    for (int mg0 = 0; mg0 < 125; mg0 += P) {
        const int Pp  = (125 - mg0 < P) ? (125 - mg0) : P;
        const int mpx = (Pp + 7) / 8;
        interp_kernel<<<Pp * NKSTEPS, 256, 0, stream>>>(signal, bc_idx, bc_w, Ag, mg0);
        gemm_kernel<<<32 * mpx, 256, 0, stream>>>(Ag, W1g, bias1, S, normsq, mg0, Pp, mpx);
    }
    pool_kernel<false><<<2500, 256, 0, stream>>>(S, normsq, gamma1, beta1, nullptr, s1);

    // stage 2
    for (int mg0 = 0; mg0 < 125; mg0 += P) {
        const int Pp  = (125 - mg0 < P) ? (125 - mg0) : P;
        const int mpx = (Pp + 7) / 8;
        interp_kernel<<<Pp * NKSTEPS, 256, 0, stream>>>(s1, bc_idx, bc_w, Ag, mg0);
        gemm_kernel<<<32 * mpx, 256, 0, stream>>>(Ag, W2g, bias2, S, normsq, mg0, Pp, mpx);
    }
    pool_kernel<true><<<2500, 256, 0, stream>>>(S, normsq, gamma2, beta2, signal, out);
}

// Round 8
// 322.363 us; speedup vs baseline: 4.6198x; 1.0788x over previous
//
#include <hip/hip_runtime.h>

// Problem constants (fixed by reference)
#define NVV 10000    // vertices
#define NKSTEPS 80   // 2560 / 32
#define BN_INV 0.99950037468777316f

#define AS1 __attribute__((address_space(1)))
#define AS3 __attribute__((address_space(3)))

typedef float f32x4 __attribute__((ext_vector_type(4)));
typedef short short8 __attribute__((ext_vector_type(8)));
typedef unsigned short ushort;

// A chunk: [mt 5][sp 2][qk 4][mm 16][kk 8] ushort = 5120 ushorts = 10240 B
#define ACH_USH 5120
#define ACH_B   10240
// W chunk (per kstep,strip): [nt 8][sp 2][q 4][l16 16][kk 8] = 8192 ushorts = 16384 B
#define WCH_B   16384

// ---------------------------------------------------------------------------
// Split a f32 into bf16 (RNE) + f32 remainder (exact).
__device__ __forceinline__ ushort bsplit(float v, float& rem) {
    unsigned u = __float_as_uint(v);
    unsigned r = (u + 0x7fffu + ((u >> 16) & 1u)) & 0xffff0000u;
    rem = v - __uint_as_float(r);
    return (ushort)(r >> 16);
}

// blend 3 gathered float4 rows, split-2 (RNE+RNE) to bf16 planes, store frag layout
__device__ __forceinline__ void interp_store2(ushort* __restrict__ dstp, int it,
                                              const float4& g0, const float4& g1, const float4& g2,
                                              float w0, float w1, float w2) {
    const int m = it >> 3, kq = it & 7;
    const float av[4] = {g0.x, g0.y, g0.z, g0.w};
    const float bv[4] = {g1.x, g1.y, g1.z, g1.w};
    const float cv[4] = {g2.x, g2.y, g2.z, g2.w};
    ushort h1[4], h2[4];
    #pragma unroll
    for (int e = 0; e < 4; ++e) {
        const float vv = w0 * av[e] + w1 * bv[e] + w2 * cv[e];
        float r1, r2;
        h1[e] = bsplit(vv, r1); h2[e] = bsplit(r1, r2);
    }
    const int mt = m >> 4, mm = m & 15, qk = kq >> 1, hf = kq & 1;
    const int o0 = ((mt * 2 + 0) * 4 + qk) * 128 + mm * 8 + hf * 4;   // ushort units
    *(uint2*)(dstp + o0)       = make_uint2((unsigned)h1[0] | ((unsigned)h1[1] << 16),
                                            (unsigned)h1[2] | ((unsigned)h1[3] << 16));
    *(uint2*)(dstp + o0 + 512) = make_uint2((unsigned)h2[0] | ((unsigned)h2[1] << 16),
                                            (unsigned)h2[2] | ((unsigned)h2[3] << 16));
}

// ---------------------------------------------------------------------------
// W global layout (per stage): [kstep 80][strip 4] chunks of 16384 B.
// w = w1 + w2 (2 RNE planes; residual <= 2^-16 relative).
__global__ void build_w_kernel(const float* __restrict__ t1,
                               const float* __restrict__ t2,
                               ushort* __restrict__ W1g,
                               ushort* __restrict__ W2g) {
    const int k = blockIdx.x;       // 0..2559
    const int n = threadIdx.x;      // 0..511
    const float* T  = blockIdx.y ? t2 : t1;
    ushort*      Wg = blockIdx.y ? W2g : W1g;
    const int r = k >> 9, a = (k >> 6) & 7, c = k & 63;
    const int o = n >> 6, t = n & 63;
    const float w = T[((t * 5 + r) * 8 + ((o + a) & 7)) * 64 + c];
    float r1, r2;
    const ushort h1 = bsplit(w, r1);
    const ushort h2 = bsplit(r1, r2);
    const int kstep = k >> 5, kw = k & 31, q = kw >> 3, kk = kw & 7;
    const int strip = n >> 7, nl = n & 127, nt = nl >> 4, l16 = nl & 15;
    const size_t base = (size_t)(kstep * 4 + strip) * 8192;
    const int off = ((nt * 2 + 0) * 4 + q) * 128 + l16 * 8 + kk;
    Wg[base + off]       = h1;      // sp stride = 512 ushorts
    Wg[base + off + 512] = h2;
}

// ---------------------------------------------------------------------------
// Materialize interp (gather+blend) as 2 RNE bf16 split planes, A-frag layout.
// One block per (mg-local, kstep) chunk of 10240 B.
__global__ void interp_kernel(const float* __restrict__ src,
                              const int*   __restrict__ bc_idx,
                              const float* __restrict__ bc_w,
                              ushort*      __restrict__ Ag,
                              int mg0) {
    const int cid = blockIdx.x;            // pass-local chunk id
    const int mgl = cid / NKSTEPS;
    const int ks  = cid % NKSTEPS;
    const int mg  = mg0 + mgl;
    const int x   = threadIdx.x;
    ushort* chunk = Ag + (size_t)cid * ACH_USH;
    const int ra = ks >> 1;
    #pragma unroll
    for (int s = 0; s < 3; ++s) {
        const int it = x + 256 * s;        // 640 items = 80 rows x 8 k-quads
        if (it < 640) {
            const int m = it >> 3, kq = it & 7;
            const int v = mg * 80 + m;
            const int*   ip = bc_idx + v * 120 + ra * 3;
            const float* wp = bc_w  + v * 120 + ra * 3;
            const int c0 = (ks & 1) * 32 + kq * 4;
            const float4 g0 = *(const float4*)(src + (size_t)ip[0] * 64 + c0);
            const float4 g1 = *(const float4*)(src + (size_t)ip[1] * 64 + c0);
            const float4 g2 = *(const float4*)(src + (size_t)ip[2] * 64 + c0);
            interp_store2(chunk, it, g0, g1, g2, wp[0], wp[1], wp[2]);
        }
    }
}

// ---------------------------------------------------------------------------
// 3-product split MFMA GEMM, fully double-buffered, ONE barrier per kstep.
// Products {a1w1, a1w2, a2w1}; dropped a2w2 <= 2^-16|a||w| per term (same
// class as the split residuals already accepted; output floor is bf16 ulp).
// Block = 80 rows x 128 cols. XCD-pinned: xcd = b&7 owns a contiguous mg
// range so all 4 strip-blocks of an mg share one L2.
__global__ __launch_bounds__(256, 3)
void gemm_kernel(const ushort* __restrict__ Ag,
                 const ushort* __restrict__ Wg,
                 const float* __restrict__ bias,     // (64)
                 float*       __restrict__ S,        // (V,512)
                 float*       __restrict__ normsq,   // (V,8)
                 int mg0, int Pp, int mpx) {
    __shared__ ushort sW[2][8192];    // 2 x 16384 B
    __shared__ ushort sA[2][ACH_USH]; // 2 x 10240 B   total 53248 B
    const int x = threadIdx.x;
    const int b = blockIdx.x;
    const int xcd  = b & 7;
    const int rest = b >> 3;
    const int strip = rest & 3;
    const int mgl_l = rest >> 2;
    const int mg_local = xcd * mpx + mgl_l;
    if (mg_local >= Pp) return;
    const int mg    = mg0 + mg_local;
    const int Mbase = mg * 80;
    const int wj  = x >> 6;
    const int l16 = x & 15;
    const int q   = (x & 63) >> 4;

    f32x4 d[5][2] = {};               // 40 f32 accumulators

    const char* gWb = (const char*)Wg;
    const char* gAb = (const char*)Ag + (size_t)mg_local * NKSTEPS * ACH_B;

    // ---- prologue: DMA W(0), A(0) into buffer 0 ----
    {
        const char* gw = gWb + (size_t)(0 * 4 + strip) * WCH_B;
        char*       lw = (char*)sW[0];
        #pragma unroll
        for (int j = 0; j < 4; ++j)
            __builtin_amdgcn_global_load_lds((AS1 const void*)(gw + (x + 256 * j) * 16),
                                             (AS3 void*)(lw + (x + 256 * j) * 16), 16, 0, 0);
        const char* ga = gAb;
        char*       la = (char*)sA[0];
        #pragma unroll
        for (int j = 0; j < 3; ++j) {
            const int it = x + 256 * j;
            if (it < 640)
                __builtin_amdgcn_global_load_lds((AS1 const void*)(ga + it * 16),
                                                 (AS3 void*)(la + it * 16), 16, 0, 0);
        }
    }
    __syncthreads();

    // ---- main loop: 1 barrier per kstep ----
    for (int ks = 0; ks < NKSTEPS; ++ks) {
        const int cur = ks & 1, nxt = cur ^ 1;
        if (ks + 1 < NKSTEPS) {
            const char* gw = gWb + (size_t)((ks + 1) * 4 + strip) * WCH_B;
            char*       lw = (char*)sW[nxt];
            #pragma unroll
            for (int j = 0; j < 4; ++j)
                __builtin_amdgcn_global_load_lds((AS1 const void*)(gw + (x + 256 * j) * 16),
                                                 (AS3 void*)(lw + (x + 256 * j) * 16), 16, 0, 0);
            const char* ga = gAb + (size_t)(ks + 1) * ACH_B;
            char*       la = (char*)sA[nxt];
            #pragma unroll
            for (int j = 0; j < 3; ++j) {
                const int it = x + 256 * j;
                if (it < 640)
                    __builtin_amdgcn_global_load_lds((AS1 const void*)(ga + it * 16),
                                                     (AS3 void*)(la + it * 16), 16, 0, 0);
            }
        }

        // MFMA: 3 products {a1w1, a1w2, a2w1} per (mt, nt)
        short8 w1f[2], w2f[2];
        #pragma unroll
        for (int nt = 0; nt < 2; ++nt) {
            const int ntg = 2 * wj + nt;
            w1f[nt] = *(const short8*)(sW[cur] + ((ntg * 2 + 0) * 4 + q) * 128 + l16 * 8);
            w2f[nt] = *(const short8*)(sW[cur] + ((ntg * 2 + 1) * 4 + q) * 128 + l16 * 8);
        }
        #pragma unroll
        for (int mt = 0; mt < 5; ++mt) {
            const short8 a1 = *(const short8*)(sA[cur] + ((mt * 2 + 0) * 4 + q) * 128 + l16 * 8);
            const short8 a2 = *(const short8*)(sA[cur] + ((mt * 2 + 1) * 4 + q) * 128 + l16 * 8);
            #pragma unroll
            for (int nt = 0; nt < 2; ++nt) {
                d[mt][nt] = __builtin_amdgcn_mfma_f32_16x16x32_bf16(a1, w1f[nt], d[mt][nt], 0, 0, 0);
                d[mt][nt] = __builtin_amdgcn_mfma_f32_16x16x32_bf16(a1, w2f[nt], d[mt][nt], 0, 0, 0);
                d[mt][nt] = __builtin_amdgcn_mfma_f32_16x16x32_bf16(a2, w1f[nt], d[mt][nt], 0, 0, 0);
            }
        }
        __syncthreads();   // drains DMA(ks+1) (covered by MFMA phase) + closes reads
    }

    // ---- epilogue: +bias, store S, norms^2 -> normsq (sN aliases sA) ----
    float* sN = (float*)sA;   // [wj 4][m 80]
    float bs[2];
    #pragma unroll
    for (int nt = 0; nt < 2; ++nt)
        bs[nt] = bias[(32 * wj + 16 * nt + l16) & 63];

    float p[5][4];
    #pragma unroll
    for (int mt = 0; mt < 5; ++mt)
        #pragma unroll
        for (int r = 0; r < 4; ++r) p[mt][r] = 0.0f;

    #pragma unroll
    for (int mt = 0; mt < 5; ++mt) {
        #pragma unroll
        for (int nt = 0; nt < 2; ++nt) {
            #pragma unroll
            for (int r = 0; r < 4; ++r) {
                const float val = d[mt][nt][r] + bs[nt];
                const int mglob = Mbase + mt * 16 + q * 4 + r;
                const int nglob = strip * 128 + wj * 32 + nt * 16 + l16;
                S[(size_t)mglob * 512 + nglob] = val;
                p[mt][r] += val * val;
            }
        }
    }
    #pragma unroll
    for (int mt = 0; mt < 5; ++mt)
        #pragma unroll
        for (int r = 0; r < 4; ++r) {
            float v = p[mt][r];
            v += __shfl_xor(v, 1, 64);
            v += __shfl_xor(v, 2, 64);
            v += __shfl_xor(v, 4, 64);
            v += __shfl_xor(v, 8, 64);
            p[mt][r] = v;
        }
    if (l16 == 0) {
        #pragma unroll
        for (int mt = 0; mt < 5; ++mt)
            #pragma unroll
            for (int r = 0; r < 4; ++r)
                sN[wj * 80 + mt * 16 + q * 4 + r] = p[mt][r];
    }
    __syncthreads();
    if (x < 80) {
        const int v = Mbase + x;
        normsq[(size_t)v * 8 + strip * 2]     = sN[0 * 80 + x] + sN[1 * 80 + x];
        normsq[(size_t)v * 8 + strip * 2 + 1] = sN[2 * 80 + x] + sN[3 * 80 + x];
    }
}

// ---------------------------------------------------------------------------
// Angular max-pool + BN (+residual) + ReLU. One thread per (v, t).
template<bool RES>
__global__ void pool_kernel(const float* __restrict__ S,
                            const float* __restrict__ normsq,
                            const float* __restrict__ gamma,
                            const float* __restrict__ beta,
                            const float* __restrict__ resid,
                            float*       __restrict__ dst) {
    const int gid = blockIdx.x * 256 + threadIdx.x;   // 640000 = 2500*256
    const int v = gid >> 6, t = gid & 63;
    const float* nv = normsq + (size_t)v * 8;
    float bv = nv[0];
    int   bj = 0;
    #pragma unroll
    for (int j = 1; j < 8; ++j) {
        const float tv = nv[j];
        if (tv > bv) { bv = tv; bj = j; }   // first-max tie-break (jnp.argmax)
    }
    const float val = S[(size_t)v * 512 + bj * 64 + t];
    float r = gamma[t] * (val * BN_INV) + beta[t];
    if (RES) r += resid[(size_t)v * 64 + t];
    dst[(size_t)v * 64 + t] = fmaxf(r, 0.0f);
}

// ---------------------------------------------------------------------------
extern "C" void kernel_launch(void* const* d_in, const int* in_sizes, int n_in,
                              void* d_out, int out_size, void* d_ws, size_t ws_size,
                              hipStream_t stream) {
    const float* signal = (const float*)d_in[0];
    const float* bc_w   = (const float*)d_in[1];
    const float* t1     = (const float*)d_in[2];
    const float* bias1  = (const float*)d_in[3];
    const float* gamma1 = (const float*)d_in[4];
    const float* beta1  = (const float*)d_in[5];
    const float* t2     = (const float*)d_in[6];
    const float* bias2  = (const float*)d_in[7];
    const float* gamma2 = (const float*)d_in[8];
    const float* beta2  = (const float*)d_in[9];
    const int*   bc_idx = (const int*)d_in[10];

    // ws: W1g 5.24 MB | W2g 5.24 MB | S 20.48 MB | normsq 0.32 MB | s1 2.56 MB | Ag (rest)
    const size_t WSTG = (size_t)NKSTEPS * 4 * 8192;       // ushorts per stage W
    ushort* W1g = (ushort*)d_ws;
    ushort* W2g = W1g + WSTG;
    float* S      = (float*)(W2g + WSTG);
    float* normsq = S + (size_t)NVV * 512;
    float* s1     = normsq + (size_t)NVV * 8;
    ushort* Ag    = (ushort*)(s1 + (size_t)NVV * 64);
    float* out    = (float*)d_out;

    // pass-chunk the materialized interp to fit ws_size (full A = 102.4 MB)
    const size_t used  = (size_t)((char*)Ag - (char*)d_ws);
    const size_t avail = ws_size > used ? ws_size - used : 0;
    int P = (int)(avail / ((size_t)NKSTEPS * ACH_B));     // mgs per pass
    if (P > 125) P = 125;
    if (P < 1)  P = 1;

    build_w_kernel<<<dim3(2560, 2), 512, 0, stream>>>(t1, t2, W1g, W2g);

    // stage 1
    for (int mg0 = 0; mg0 < 125; mg0 += P) {
        const int Pp  = (125 - mg0 < P) ? (125 - mg0) : P;
        const int mpx = (Pp + 7) / 8;
        interp_kernel<<<Pp * NKSTEPS, 256, 0, stream>>>(signal, bc_idx, bc_w, Ag, mg0);
        gemm_kernel<<<32 * mpx, 256, 0, stream>>>(Ag, W1g, bias1, S, normsq, mg0, Pp, mpx);
    }
    pool_kernel<false><<<2500, 256, 0, stream>>>(S, normsq, gamma1, beta1, nullptr, s1);

    // stage 2
    for (int mg0 = 0; mg0 < 125; mg0 += P) {
        const int Pp  = (125 - mg0 < P) ? (125 - mg0) : P;
        const int mpx = (Pp + 7) / 8;
        interp_kernel<<<Pp * NKSTEPS, 256, 0, stream>>>(s1, bc_idx, bc_w, Ag, mg0);
        gemm_kernel<<<32 * mpx, 256, 0, stream>>>(Ag, W2g, bias2, S, normsq, mg0, Pp, mpx);
    }
    pool_kernel<true><<<2500, 256, 0, stream>>>(S, normsq, gamma2, beta2, signal, out);
}